// Round 7
// baseline (561.257 us; speedup 1.0000x reference)
//
#include <hip/hip_runtime.h>
#include <hip/hip_bf16.h>

typedef __attribute__((ext_vector_type(4)))  float  floatx4;
typedef __attribute__((ext_vector_type(16))) float  floatx16;
typedef __attribute__((ext_vector_type(8)))  short  shortx8;
typedef __attribute__((ext_vector_type(4)))  short  shortx4;

// ---------- bf16 helpers (bit-level, RNE) ----------
__device__ __forceinline__ short f2bf(float f) {
    unsigned u = __float_as_uint(f);
    u += 0x7fffu + ((u >> 16) & 1u);
    return (short)(u >> 16);
}
__device__ __forceinline__ float bf2f(short s) {
    return __uint_as_float(((unsigned)(unsigned short)s) << 16);
}
__device__ __forceinline__ float fast_exp2(float x) {
#if __has_builtin(__builtin_amdgcn_exp2f)
    return __builtin_amdgcn_exp2f(x);
#else
    return exp2f(x);
#endif
}

// ---------- async global->LDS, 16B per lane ----------
__device__ __forceinline__ void load_lds16(const void* g, void* l) {
    __builtin_amdgcn_global_load_lds(
        (const __attribute__((address_space(1))) unsigned int*)g,
        (__attribute__((address_space(3))) unsigned int*)l,
        16, 0, 0);
}

// =====================================================================
// Weight transpose+convert: src fp32 [K][N] -> dst bf16 [N][K]
// =====================================================================
__global__ __launch_bounds__(256)
void transpose_w(const float* __restrict__ src, short* __restrict__ dst, int K, int N)
{
    __shared__ __align__(16) float tile[32][33];
    const int n0 = blockIdx.x * 32, k0 = blockIdx.y * 32;
    const int tx = threadIdx.x & 31, ty = threadIdx.x >> 5;   // ty 0..7
    for (int i = 0; i < 32; i += 8)
        tile[ty + i][tx] = src[(size_t)(k0 + ty + i) * N + n0 + tx];
    __syncthreads();
    for (int i = 0; i < 32; i += 8)
        dst[(size_t)(n0 + ty + i) * K + k0 + tx] = f2bf(tile[tx][ty + i]);
}

// =====================================================================
// LayerNorm fp32 [8192][1024] -> bf16, 1 block/row
// =====================================================================
__global__ __launch_bounds__(256)
void ln_bf16(const float* __restrict__ x, const float* __restrict__ g,
             const float* __restrict__ be, short* __restrict__ out)
{
    const int row = blockIdx.x;
    const int tid = threadIdx.x;
    const float4 v = reinterpret_cast<const float4*>(x + (size_t)row * 1024)[tid];
    float s  = v.x + v.y + v.z + v.w;
    float ss = v.x * v.x + v.y * v.y + v.z * v.z + v.w * v.w;
    for (int off = 32; off > 0; off >>= 1) {
        s  += __shfl_down(s,  off);
        ss += __shfl_down(ss, off);
    }
    __shared__ float rs[4], rss[4];
    const int wave = tid >> 6, lane = tid & 63;
    if (lane == 0) { rs[wave] = s; rss[wave] = ss; }
    __syncthreads();
    const float S    = rs[0] + rs[1] + rs[2] + rs[3];
    const float SS   = rss[0] + rss[1] + rss[2] + rss[3];
    const float mean = S * (1.0f / 1024.0f);
    const float var  = SS * (1.0f / 1024.0f) - mean * mean;
    const float rstd = rsqrtf(var + 1e-5f);
    const float4 gg = reinterpret_cast<const float4*>(g)[tid];
    const float4 bb = reinterpret_cast<const float4*>(be)[tid];
    shortx4 o;
    o[0] = f2bf(gg.x * ((v.x - mean) * rstd) + bb.x);
    o[1] = f2bf(gg.y * ((v.y - mean) * rstd) + bb.y);
    o[2] = f2bf(gg.z * ((v.z - mean) * rstd) + bb.z);
    o[3] = f2bf(gg.w * ((v.w - mean) * rstd) + bb.w);
    *reinterpret_cast<shortx4*>(out + (size_t)row * 1024 + tid * 4) = o;
}

// =====================================================================
// 256x256 8-phase bf16 GEMM, deep-prefetch variant, optional split-K.
// C[M][N] = A[M][K] @ Bt[N][K]^T.  512 threads = 8 waves (2M x 4N),
// per-wave 128x64 output (8x4 16x16 frags), BK=64, double-buffered
// 128 KiB LDS, XOR-granule swizzle, counted vmcnt, setprio, XCD swizzle.
// All 8 next-tile global_load_lds issued in P1 (3-4 phases latency cover).
// EPI 0: store bf16
// EPI 1: +bias, relu, store bf16
// EPI 2: fp32 out = resid + acc
// EPI 3: fp32 out = resid + acc + bias
// EPI 4: atomicAdd(out, acc (+bias if split 0))  -- split-K accumulation
// =====================================================================
__device__ __forceinline__ floatx4 mfma2(shortx8 a0, shortx8 a1,
                                         shortx8 b0, shortx8 b1, floatx4 c) {
    c = __builtin_amdgcn_mfma_f32_16x16x32_bf16(a0, b0, c, 0, 0, 0);
    return __builtin_amdgcn_mfma_f32_16x16x32_bf16(a1, b1, c, 0, 0, 0);
}

template <int EPI>
__global__ __launch_bounds__(512, 2)
void gemm256(const short* __restrict__ A, const short* __restrict__ Bt,
             short* __restrict__ Cb, float* __restrict__ Cf,
             const float* __restrict__ bias, const float* __restrict__ resid,
             int M, int N, int K, int tilesN, int nsplit)
{
    extern __shared__ __align__(16) short lds[];
    short* const As0 = lds;              // 256x64 shorts = 32 KiB
    short* const Bs0 = lds + 16384;
    short* const As1 = lds + 32768;
    short* const Bs1 = lds + 49152;

    // bijective XCD-aware swizzle (m204): contiguous chunk per XCD
    int wg = blockIdx.x;
    {
        const int nwg = gridDim.x;
        const int q = nwg >> 3, r = nwg & 7;
        const int xcd = wg & 7, loc = wg >> 3;
        wg = (xcd < r ? xcd * (q + 1) : r * (q + 1) + (xcd - r) * q) + loc;
    }
    const int ntiles = gridDim.x / nsplit;
    const int sp   = wg / ntiles;            // split index (0 if nsplit==1)
    const int tile = wg - sp * ntiles;
    const int tm = tile / tilesN, tn = tile - tm * tilesN;
    const size_t bm = (size_t)tm * 256, bn = (size_t)tn * 256;
    const int Ks   = K / nsplit;             // this WG's K extent
    const int kbeg = sp * Ks;

    const int tid  = threadIdx.x;
    const int wave = tid >> 6;          // 0..7
    const int lane = tid & 63;
    const int quad = lane >> 4;         // 0..3
    const int l16  = lane & 15;
    const int wm   = wave >> 2;         // 0..1  (M wave-row)
    const int wn   = wave & 3;          // 0..3  (N wave-col)

    // fragment read offsets: row stride 64 shorts; 16B granule swizzled by row&7
    const int x7  = l16 & 7;
    const int go0 = ((quad    ) ^ x7) * 8;   // ksub 0, in shorts
    const int go1 = ((quad + 4) ^ x7) * 8;   // ksub 1
    const int aoff = (wm * 128 + l16) * 64;  // + mi*1024
    const int boff = (wn *  64 + l16) * 64;  // + ni*1024

    // staging: each call = 64 rows x 64 k; thread -> (row, logical granule)
    // pre-swizzled GLOBAL source so the linear global_load_lds dest matches
    const int rcall = tid >> 3;              // 0..63
    const int gl    = (tid & 7) ^ (rcall & 7);
    const short* srcA = A  + (bm + rcall) * (size_t)K + kbeg + gl * 8;
    const short* srcB = Bt + (bn + rcall) * (size_t)K + kbeg + gl * 8;
    const int dstw = wave * 512;             // wave's 8-row slice within a call

#define STG(dst, src, c, k0) \
    load_lds16((src) + (size_t)(c) * 64 * K + (k0), (dst) + (c) * 4096 + dstw)

    const int NT = Ks >> 6;

    // prologue: stage tile 0 (order: a0,a2,b0..b3,a1,a3 — first 6 needed at P1)
    STG(As0, srcA, 0, 0); STG(As0, srcA, 2, 0);
    STG(Bs0, srcB, 0, 0); STG(Bs0, srcB, 1, 0);
    STG(Bs0, srcB, 2, 0); STG(Bs0, srcB, 3, 0);
    STG(As0, srcA, 1, 0); STG(As0, srcA, 3, 0);

    floatx4 acc[8][4];
#pragma unroll
    for (int i = 0; i < 8; i++)
#pragma unroll
        for (int j = 0; j < 4; j++)
            acc[i][j] = (floatx4){0.f, 0.f, 0.f, 0.f};

    asm volatile("s_waitcnt vmcnt(2)" ::: "memory");   // a0,a2,b0..b3 landed
    __builtin_amdgcn_s_barrier();

    for (int t = 0; t < NT; ++t) {
        const short* Asc = (t & 1) ? As1 : As0;
        const short* Bsc = (t & 1) ? Bs1 : Bs0;
        short* Asn = (t & 1) ? As0 : As1;
        short* Bsn = (t & 1) ? Bs0 : Bs1;
        const int kn = (t + 1) << 6;
        const bool pf = (t + 1) < NT;

        shortx8 aF[4][2], bF[2][2];

        // ---- P1: (mi 0-3) x (ni 0-1); 12 ds_read + ALL 8 next-tile stages ----
#pragma unroll
        for (int mi = 0; mi < 4; ++mi) {
            aF[mi][0] = *(const shortx8*)&Asc[aoff + mi * 1024 + go0];
            aF[mi][1] = *(const shortx8*)&Asc[aoff + mi * 1024 + go1];
        }
#pragma unroll
        for (int ni = 0; ni < 2; ++ni) {
            bF[ni][0] = *(const shortx8*)&Bsc[boff + ni * 1024 + go0];
            bF[ni][1] = *(const shortx8*)&Bsc[boff + ni * 1024 + go1];
        }
        if (pf) {
            // dest buffer (t+1) was fully consumed at end of tile t-1; safe.
            STG(Asn, srcA, 0, kn); STG(Asn, srcA, 2, kn);
            STG(Bsn, srcB, 0, kn); STG(Bsn, srcB, 1, kn);
            STG(Bsn, srcB, 2, kn); STG(Bsn, srcB, 3, kn);
            STG(Asn, srcA, 1, kn); STG(Asn, srcA, 3, kn);
        }
        __builtin_amdgcn_s_barrier();
        asm volatile("s_waitcnt lgkmcnt(0)" ::: "memory");
        __builtin_amdgcn_s_setprio(1);
#pragma unroll
        for (int mi = 0; mi < 4; ++mi)
#pragma unroll
            for (int ni = 0; ni < 2; ++ni)
                acc[mi][ni] = mfma2(aF[mi][0], aF[mi][1], bF[ni][0], bF[ni][1], acc[mi][ni]);
        __builtin_amdgcn_s_setprio(0);
        __builtin_amdgcn_s_barrier();

        // ---- P2: (mi 0-3) x (ni 2-3);  4 ds_read ----
#pragma unroll
        for (int ni = 0; ni < 2; ++ni) {
            bF[ni][0] = *(const shortx8*)&Bsc[boff + (ni + 2) * 1024 + go0];
            bF[ni][1] = *(const shortx8*)&Bsc[boff + (ni + 2) * 1024 + go1];
        }
        __builtin_amdgcn_s_barrier();
        asm volatile("s_waitcnt lgkmcnt(0)" ::: "memory");
        __builtin_amdgcn_s_setprio(1);
#pragma unroll
        for (int mi = 0; mi < 4; ++mi)
#pragma unroll
            for (int ni = 0; ni < 2; ++ni)
                acc[mi][ni + 2] = mfma2(aF[mi][0], aF[mi][1], bF[ni][0], bF[ni][1], acc[mi][ni + 2]);
        __builtin_amdgcn_s_setprio(0);
        // gate this tile's a1,a3 (needed by P3). Steady state: 10 outstanding
        // (2 old + 8 new) -> vmcnt(8) retires the 2 oldest = a1,a3 of tile t.
        // Last tile: only 2 outstanding -> drain to 0.
        if (pf) asm volatile("s_waitcnt vmcnt(8)" ::: "memory");
        else    asm volatile("s_waitcnt vmcnt(0)" ::: "memory");
        __builtin_amdgcn_s_barrier();

        // ---- P3: (mi 4-7) x (ni 2-3);  8 ds_read ----
#pragma unroll
        for (int mi = 0; mi < 4; ++mi) {
            aF[mi][0] = *(const shortx8*)&Asc[aoff + (mi + 4) * 1024 + go0];
            aF[mi][1] = *(const shortx8*)&Asc[aoff + (mi + 4) * 1024 + go1];
        }
        __builtin_amdgcn_s_barrier();
        asm volatile("s_waitcnt lgkmcnt(0)" ::: "memory");
        __builtin_amdgcn_s_setprio(1);
#pragma unroll
        for (int mi = 0; mi < 4; ++mi)
#pragma unroll
            for (int ni = 0; ni < 2; ++ni)
                acc[mi + 4][ni + 2] = mfma2(aF[mi][0], aF[mi][1], bF[ni][0], bF[ni][1], acc[mi + 4][ni + 2]);
        __builtin_amdgcn_s_setprio(0);
        __builtin_amdgcn_s_barrier();

        // ---- P4: (mi 4-7) x (ni 0-1);  4 ds_read (re-read B0,B1) ----
#pragma unroll
        for (int ni = 0; ni < 2; ++ni) {
            bF[ni][0] = *(const shortx8*)&Bsc[boff + ni * 1024 + go0];
            bF[ni][1] = *(const shortx8*)&Bsc[boff + ni * 1024 + go1];
        }
        __builtin_amdgcn_s_barrier();
        asm volatile("s_waitcnt lgkmcnt(0)" ::: "memory");
        __builtin_amdgcn_s_setprio(1);
#pragma unroll
        for (int mi = 0; mi < 4; ++mi)
#pragma unroll
            for (int ni = 0; ni < 2; ++ni)
                acc[mi + 4][ni] = mfma2(aF[mi][0], aF[mi][1], bF[ni][0], bF[ni][1], acc[mi + 4][ni]);
        __builtin_amdgcn_s_setprio(0);
        // next tile's first 6 stages must have landed before its P1 reads
        asm volatile("s_waitcnt vmcnt(2)" ::: "memory");
        __builtin_amdgcn_s_barrier();
    }
#undef STG

    // epilogue (m89 C/D layout: col = l16, row = quad*4 + r)
#pragma unroll
    for (int mi = 0; mi < 8; ++mi) {
#pragma unroll
        for (int ni = 0; ni < 4; ++ni) {
            const size_t row0 = bm + wm * 128 + mi * 16 + quad * 4;
            const size_t col  = bn + wn * 64 + ni * 16 + l16;
#pragma unroll
            for (int r = 0; r < 4; ++r) {
                float v = acc[mi][ni][r];
                const size_t idx = (row0 + r) * (size_t)N + col;
                if (EPI == 0) {
                    Cb[idx] = f2bf(v);
                } else if (EPI == 1) {
                    v += bias[col];
                    Cb[idx] = f2bf(v > 0.f ? v : 0.f);
                } else if (EPI == 2) {
                    Cf[idx] = resid[idx] + v;
                } else if (EPI == 3) {
                    v += bias[col];
                    Cf[idx] = resid[idx] + v;
                } else {
                    if (sp == 0) v += bias[col];
                    atomicAdd(&Cf[idx], v);
                }
            }
        }
    }
}

// =====================================================================
// V transpose: qkv v-part -> vt[b][h][64 d][2048 s] bf16
// =====================================================================
__global__ __launch_bounds__(256)
void transpose_v(const short* __restrict__ qkv, short* __restrict__ vt)
{
    __shared__ __align__(16) short tile[64][65];
    const int st = blockIdx.x, h = blockIdx.y, b = blockIdx.z;
    const int t = threadIdx.x;
    for (int i = 0; i < 2; i++) {
        const int idx = i * 256 + t;
        const int s = idx >> 3, dg = idx & 7;
        shortx8 val = *(const shortx8*)&qkv[(size_t)(b * 2048 + st * 64 + s) * 3072
                                           + 2048 + h * 64 + dg * 8];
        for (int u = 0; u < 8; u++) tile[s][dg * 8 + u] = val[u];
    }
    __syncthreads();
    const int d = t >> 2, sg = (t & 3) * 16;
    shortx8 lo, hi;
    for (int i = 0; i < 8; i++) {
        lo[i] = tile[sg + i][d];
        hi[i] = tile[sg + 8 + i][d];
    }
    const size_t base = ((size_t)(b * 16 + h) * 64 + d) * 2048 + st * 64 + sg;
    *(shortx8*)&vt[base]     = lo;
    *(shortx8*)&vt[base + 8] = hi;
}

// =====================================================================
// Flash attention v6 (unchanged): 32x32x16 MFMA, 8 waves x 32 q-rows.
// =====================================================================
__global__ __launch_bounds__(512, 4)
void attention_kernel(const short* __restrict__ qkv, const short* __restrict__ vt,
                      short* __restrict__ ctx)
{
    const int qt = blockIdx.x, h = blockIdx.y, b = blockIdx.z;
    const int tid  = threadIdx.x;
    const int wave = tid >> 6;          // 0..7
    const int lane = tid & 63;
    const int l32  = lane & 31;
    const int hf   = lane >> 5;         // 0/1

    __shared__ __align__(16) short Ks[64 * 72];        // [kseq][d], stride 72
    __shared__ __align__(16) short Vs[64 * 72];        // [d][s],   stride 72
    __shared__ __align__(16) short Ps[8][32 * 72];     // per-wave P [q][s], stride 72

    const int q0 = qt * 256 + wave * 32;
    const float qscale = 0.125f * 1.44269504088896f;
    const short* qrow = qkv + (size_t)(b * 2048 + q0 + l32) * 3072 + h * 64;
    shortx8 qf[4];
    for (int dk = 0; dk < 4; dk++) {
        shortx8 raw = *(const shortx8*)&qrow[dk * 16 + hf * 8];
        for (int j = 0; j < 8; j++) raw[j] = f2bf(bf2f(raw[j]) * qscale);
        qf[dk] = raw;
    }

    floatx16 accO[2];
    for (int t = 0; t < 2; t++)
        for (int r = 0; r < 16; r++) accO[t][r] = 0.f;
    float lsum = 0.f;

    const short* kbase = qkv + (size_t)(b * 2048) * 3072 + 1024 + h * 64;
    const short* vbase = vt + ((size_t)(b * 16 + h) * 64) * 2048;
    short* const psw = &Ps[wave][0];
    unsigned* const pswd = (unsigned*)psw;

    const int ss = tid >> 3, sdg = tid & 7;

    for (int kt = 0; kt < 32; ++kt) {
        __syncthreads();
        {
            shortx8 kv = *(const shortx8*)&kbase[(size_t)(kt * 64 + ss) * 3072 + sdg * 8];
            *(shortx8*)&Ks[ss * 72 + sdg * 8] = kv;
            shortx8 vv = *(const shortx8*)&vbase[(size_t)ss * 2048 + kt * 64 + sdg * 8];
            *(shortx8*)&Vs[ss * 72 + sdg * 8] = vv;
        }
        __syncthreads();

        for (int t = 0; t < 2; t++) {
            floatx16 c;
            for (int r = 0; r < 16; r++) c[r] = 0.f;
            for (int dk = 0; dk < 4; dk++) {
                shortx8 kf = *(const shortx8*)&Ks[(t * 32 + l32) * 72 + dk * 16 + hf * 8];
                c = __builtin_amdgcn_mfma_f32_32x32x16_bf16(kf, qf[dk], c, 0, 0, 0);
            }
            for (int R = 0; R < 4; R++) {
                float2 a, bb;
                a.x  = fast_exp2(c[4 * R + 0]);
                a.y  = fast_exp2(c[4 * R + 1]);
                bb.x = fast_exp2(c[4 * R + 2]);
                bb.y = fast_exp2(c[4 * R + 3]);
                lsum += (a.x + a.y) + (bb.x + bb.y);
                union { __hip_bfloat162 h2[2]; uint2 u; } pk;
                pk.h2[0] = __float22bfloat162_rn(a);
                pk.h2[1] = __float22bfloat162_rn(bb);
                *(uint2*)&pswd[l32 * 36 + t * 16 + 4 * R + 2 * hf] = pk.u;
            }
        }
        asm volatile("s_waitcnt lgkmcnt(0)" ::: "memory");

        shortx8 pf[4];
        for (int sk = 0; sk < 4; sk++)
            pf[sk] = *(const shortx8*)&psw[l32 * 72 + sk * 16 + hf * 8];

        for (int t = 0; t < 2; t++) {
            floatx16 c = accO[t];
            for (int sk = 0; sk < 4; sk++) {
                shortx8 vf = *(const shortx8*)&Vs[(t * 32 + l32) * 72 + sk * 16 + hf * 8];
                c = __builtin_amdgcn_mfma_f32_32x32x16_bf16(vf, pf[sk], c, 0, 0, 0);
            }
            accO[t] = c;
        }
    }

    const float lfull = lsum + __shfl_xor(lsum, 32);
    const float inv = 1.0f / lfull;
    const size_t crow = (size_t)(b * 2048 + q0 + l32) * 1024 + h * 64;
    for (int t = 0; t < 2; t++)
        for (int R = 0; R < 4; R++) {
            float2 a, bb;
            a.x  = accO[t][4 * R + 0] * inv;
            a.y  = accO[t][4 * R + 1] * inv;
            bb.x = accO[t][4 * R + 2] * inv;
            bb.y = accO[t][4 * R + 3] * inv;
            union { __hip_bfloat162 h2[2]; uint2 u; } pk;
            pk.h2[0] = __float22bfloat162_rn(a);
            pk.h2[1] = __float22bfloat162_rn(bb);
            *(uint2*)&ctx[crow + t * 32 + 8 * R + 4 * hf] = pk.u;
        }
}

// =====================================================================
// launch
// =====================================================================
extern "C" void kernel_launch(void* const* d_in, const int* in_sizes, int n_in,
                              void* d_out, int out_size, void* d_ws, size_t ws_size,
                              hipStream_t stream)
{
    const float* x   = (const float*)d_in[0];
    const float* Wq  = (const float*)d_in[1];
    const float* Wk  = (const float*)d_in[2];
    const float* Wv  = (const float*)d_in[3];
    const float* Wo  = (const float*)d_in[4];
    const float* W1  = (const float*)d_in[5];
    const float* b1  = (const float*)d_in[6];
    const float* W2  = (const float*)d_in[7];
    const float* b2  = (const float*)d_in[8];
    const float* g1  = (const float*)d_in[9];
    const float* be1 = (const float*)d_in[10];
    const float* g2  = (const float*)d_in[11];
    const float* be2 = (const float*)d_in[12];
    float* out = (float*)d_out;
    char*  ws  = (char*)d_ws;

    const size_t MiB = 1u << 20;
    short* regA   = (short*)(ws);                 // 16 MiB: ln1 -> ctx -> ln2
    short* qkv    = (short*)(ws + 16 * MiB);      // 48 MiB
    short* vt     = (short*)(ws + 64 * MiB);      // 16 MiB
    short* ff1    = qkv;                          // 64 MiB alias (qkv+vt dead)
    short* Wqkv_t = (short*)(ws + 80 * MiB);      // 6 MiB
    short* Wo_t   = (short*)(ws + 86 * MiB);      // 2 MiB
    short* W1_t   = (short*)(ws + 88 * MiB);      // 8 MiB
    short* W2_t   = (short*)(ws + 96 * MiB);      // 8 MiB  (total 104 MiB)

    const dim3 blk(256);
    const unsigned LDSB = 131072;                 // 128 KiB dynamic LDS

    static int attr_once = []() {
        hipFuncSetAttribute(reinterpret_cast<const void*>(gemm256<0>),
                            hipFuncAttributeMaxDynamicSharedMemorySize, 131072);
        hipFuncSetAttribute(reinterpret_cast<const void*>(gemm256<1>),
                            hipFuncAttributeMaxDynamicSharedMemorySize, 131072);
        hipFuncSetAttribute(reinterpret_cast<const void*>(gemm256<2>),
                            hipFuncAttributeMaxDynamicSharedMemorySize, 131072);
        hipFuncSetAttribute(reinterpret_cast<const void*>(gemm256<4>),
                            hipFuncAttributeMaxDynamicSharedMemorySize, 131072);
        return 0;
    }();
    (void)attr_once;

    // weights -> bf16 BT layout
    transpose_w<<<dim3(32, 32),  blk, 0, stream>>>(Wq, Wqkv_t,                  1024, 1024);
    transpose_w<<<dim3(32, 32),  blk, 0, stream>>>(Wk, Wqkv_t + 1024 * 1024,    1024, 1024);
    transpose_w<<<dim3(32, 32),  blk, 0, stream>>>(Wv, Wqkv_t + 2 * 1024 * 1024,1024, 1024);
    transpose_w<<<dim3(32, 32),  blk, 0, stream>>>(Wo, Wo_t,                    1024, 1024);
    transpose_w<<<dim3(128, 32), blk, 0, stream>>>(W1, W1_t,                    1024, 4096);
    transpose_w<<<dim3(32, 128), blk, 0, stream>>>(W2, W2_t,                    4096, 1024);

    // LN1
    ln_bf16<<<8192, blk, 0, stream>>>(x, g1, be1, regA);
    // QKV: [8192,1024] @ [3072,1024]^T  -> 32x12 = 384 WGs
    gemm256<0><<<dim3(384), dim3(512), LDSB, stream>>>(regA, Wqkv_t, qkv, nullptr,
                                                       nullptr, nullptr, 8192, 3072, 1024, 12, 1);
    // V^T
    transpose_v<<<dim3(32, 16, 4), blk, 0, stream>>>(qkv, vt);
    // attention -> ctx (regA)
    attention_kernel<<<dim3(8, 16, 4), dim3(512), 0, stream>>>(qkv, vt, regA);
    // attn_out @ Wo + x -> out (fp32): 32x4 = 128 WGs
    gemm256<2><<<dim3(128), dim3(512), LDSB, stream>>>(regA, Wo_t, nullptr, out,
                                                       nullptr, x, 8192, 1024, 1024, 4, 1);
    // LN2 -> regA
    ln_bf16<<<8192, blk, 0, stream>>>(out, g2, be2, regA);
    // FF1: relu(ln2 @ W1 + b1) -> ff1 (bf16): 32x16 = 512 WGs
    gemm256<1><<<dim3(512), dim3(512), LDSB, stream>>>(regA, W1_t, ff1, nullptr,
                                                       b1, nullptr, 8192, 4096, 1024, 16, 1);
    // FF2: out += ff1 @ W2 + b2  -- split-K=2, atomic accumulation into out
    // (out already holds attn_residual from the Wo GEMM): 32x4x2 = 256 WGs
    gemm256<4><<<dim3(256), dim3(512), LDSB, stream>>>(ff1, W2_t, nullptr, out,
                                                       b2, nullptr, 8192, 1024, 4096, 4, 2);
}

// Round 8
// 542.498 us; speedup vs baseline: 1.0346x; 1.0346x over previous
//
#include <hip/hip_runtime.h>
#include <hip/hip_bf16.h>

typedef __attribute__((ext_vector_type(4)))  float  floatx4;
typedef __attribute__((ext_vector_type(16))) float  floatx16;
typedef __attribute__((ext_vector_type(8)))  short  shortx8;
typedef __attribute__((ext_vector_type(4)))  short  shortx4;

// ---------- bf16 helpers (bit-level, RNE) ----------
__device__ __forceinline__ short f2bf(float f) {
    unsigned u = __float_as_uint(f);
    u += 0x7fffu + ((u >> 16) & 1u);
    return (short)(u >> 16);
}
__device__ __forceinline__ float bf2f(short s) {
    return __uint_as_float(((unsigned)(unsigned short)s) << 16);
}
__device__ __forceinline__ float fast_exp2(float x) {
#if __has_builtin(__builtin_amdgcn_exp2f)
    return __builtin_amdgcn_exp2f(x);
#else
    return exp2f(x);
#endif
}

// ---------- async global->LDS, 16B per lane ----------
__device__ __forceinline__ void load_lds16(const void* g, void* l) {
    __builtin_amdgcn_global_load_lds(
        (const __attribute__((address_space(1))) unsigned int*)g,
        (__attribute__((address_space(3))) unsigned int*)l,
        16, 0, 0);
}

// =====================================================================
// Weight transpose+convert: src fp32 [K][N] -> dst bf16 [N][K]
// =====================================================================
__global__ __launch_bounds__(256)
void transpose_w(const float* __restrict__ src, short* __restrict__ dst, int K, int N)
{
    __shared__ __align__(16) float tile[32][33];
    const int n0 = blockIdx.x * 32, k0 = blockIdx.y * 32;
    const int tx = threadIdx.x & 31, ty = threadIdx.x >> 5;   // ty 0..7
    for (int i = 0; i < 32; i += 8)
        tile[ty + i][tx] = src[(size_t)(k0 + ty + i) * N + n0 + tx];
    __syncthreads();
    for (int i = 0; i < 32; i += 8)
        dst[(size_t)(n0 + ty + i) * K + k0 + tx] = f2bf(tile[tx][ty + i]);
}

// =====================================================================
// LayerNorm fp32 [8192][1024] -> bf16, 1 block/row
// =====================================================================
__global__ __launch_bounds__(256)
void ln_bf16(const float* __restrict__ x, const float* __restrict__ g,
             const float* __restrict__ be, short* __restrict__ out)
{
    const int row = blockIdx.x;
    const int tid = threadIdx.x;
    const float4 v = reinterpret_cast<const float4*>(x + (size_t)row * 1024)[tid];
    float s  = v.x + v.y + v.z + v.w;
    float ss = v.x * v.x + v.y * v.y + v.z * v.z + v.w * v.w;
    for (int off = 32; off > 0; off >>= 1) {
        s  += __shfl_down(s,  off);
        ss += __shfl_down(ss, off);
    }
    __shared__ float rs[4], rss[4];
    const int wave = tid >> 6, lane = tid & 63;
    if (lane == 0) { rs[wave] = s; rss[wave] = ss; }
    __syncthreads();
    const float S    = rs[0] + rs[1] + rs[2] + rs[3];
    const float SS   = rss[0] + rss[1] + rss[2] + rss[3];
    const float mean = S * (1.0f / 1024.0f);
    const float var  = SS * (1.0f / 1024.0f) - mean * mean;
    const float rstd = rsqrtf(var + 1e-5f);
    const float4 gg = reinterpret_cast<const float4*>(g)[tid];
    const float4 bb = reinterpret_cast<const float4*>(be)[tid];
    shortx4 o;
    o[0] = f2bf(gg.x * ((v.x - mean) * rstd) + bb.x);
    o[1] = f2bf(gg.y * ((v.y - mean) * rstd) + bb.y);
    o[2] = f2bf(gg.z * ((v.z - mean) * rstd) + bb.z);
    o[3] = f2bf(gg.w * ((v.w - mean) * rstd) + bb.w);
    *reinterpret_cast<shortx4*>(out + (size_t)row * 1024 + tid * 4) = o;
}

// =====================================================================
// 256x256 bf16 GEMM, m201-faithful: 8 phases / TWO K-tiles per iteration
// with STATIC double-buffer pointers (compiler can disambiguate ds_reads
// from outstanding global_load_lds DMA -> counted vmcnt survives).
// 512 threads = 8 waves (2M x 4N), per-wave 128x64, BK=64, 128 KiB LDS,
// XOR-granule swizzle, setprio, XCD swizzle, optional split-K.
// EPI 0: store bf16
// EPI 1: +bias, relu, store bf16
// EPI 2: fp32 out = resid + acc
// EPI 3: fp32 out = resid + acc + bias
// EPI 4: atomicAdd(out, acc (+bias if split 0))  -- split-K accumulation
// =====================================================================
__device__ __forceinline__ floatx4 mfma2(shortx8 a0, shortx8 a1,
                                         shortx8 b0, shortx8 b1, floatx4 c) {
    c = __builtin_amdgcn_mfma_f32_16x16x32_bf16(a0, b0, c, 0, 0, 0);
    return __builtin_amdgcn_mfma_f32_16x16x32_bf16(a1, b1, c, 0, 0, 0);
}

template <int EPI>
__global__ __launch_bounds__(512, 2)
void gemm256(const short* __restrict__ A, const short* __restrict__ Bt,
             short* __restrict__ Cb, float* __restrict__ Cf,
             const float* __restrict__ bias, const float* __restrict__ resid,
             int M, int N, int K, int tilesN, int nsplit)
{
    extern __shared__ __align__(16) short lds[];
    short* const As0 = lds;              // 256x64 shorts = 32 KiB
    short* const Bs0 = lds + 16384;
    short* const As1 = lds + 32768;
    short* const Bs1 = lds + 49152;

    // bijective XCD-aware swizzle (m204): contiguous chunk per XCD
    int wg = blockIdx.x;
    {
        const int nwg = gridDim.x;
        const int q = nwg >> 3, r = nwg & 7;
        const int xcd = wg & 7, loc = wg >> 3;
        wg = (xcd < r ? xcd * (q + 1) : r * (q + 1) + (xcd - r) * q) + loc;
    }
    const int ntiles = gridDim.x / nsplit;
    const int sp   = wg / ntiles;            // split index (0 if nsplit==1)
    const int tile = wg - sp * ntiles;
    const int tm = tile / tilesN, tn = tile - tm * tilesN;
    const size_t bm = (size_t)tm * 256, bn = (size_t)tn * 256;
    const int Ks   = K / nsplit;             // this WG's K extent
    const int kbeg = sp * Ks;

    const int tid  = threadIdx.x;
    const int wave = tid >> 6;          // 0..7
    const int lane = tid & 63;
    const int quad = lane >> 4;         // 0..3
    const int l16  = lane & 15;
    const int wm   = wave >> 2;         // 0..1  (M wave-row)
    const int wn   = wave & 3;          // 0..3  (N wave-col)

    // fragment read offsets: row stride 64 shorts; 16B granule swizzled by row&7
    const int x7  = l16 & 7;
    const int go0 = ((quad    ) ^ x7) * 8;   // ksub 0, in shorts
    const int go1 = ((quad + 4) ^ x7) * 8;   // ksub 1
    const int aoff = (wm * 128 + l16) * 64;  // + mi*1024
    const int boff = (wn *  64 + l16) * 64;  // + ni*1024

    // staging: each call = 64 rows x 64 k; thread -> (row, logical granule)
    // pre-swizzled GLOBAL source so the linear global_load_lds dest matches
    const int rcall = tid >> 3;              // 0..63
    const int gl    = (tid & 7) ^ (rcall & 7);
    const short* srcA = A  + (bm + rcall) * (size_t)K + kbeg + gl * 8;
    const short* srcB = Bt + (bn + rcall) * (size_t)K + kbeg + gl * 8;
    const int dstw = wave * 512;             // wave's 8-row slice within a call

#define STG(dst, src, c, k0) \
    load_lds16((src) + (size_t)(c) * 64 * K + (k0), (dst) + (c) * 4096 + dstw)

    const int NT = Ks >> 6;                  // even for all our shapes

    // prologue: stage tile 0 into buf0 (order a0,a2,b0..b3,a1,a3)
    STG(As0, srcA, 0, 0); STG(As0, srcA, 2, 0);
    STG(Bs0, srcB, 0, 0); STG(Bs0, srcB, 1, 0);
    STG(Bs0, srcB, 2, 0); STG(Bs0, srcB, 3, 0);
    STG(As0, srcA, 1, 0); STG(As0, srcA, 3, 0);

    floatx4 acc[8][4];
#pragma unroll
    for (int i = 0; i < 8; i++)
#pragma unroll
        for (int j = 0; j < 4; j++)
            acc[i][j] = (floatx4){0.f, 0.f, 0.f, 0.f};

    asm volatile("s_waitcnt vmcnt(2)" ::: "memory");   // a0,a2,b0..b3 landed
    __builtin_amdgcn_s_barrier();

    // One K-tile: 4 phases; reads bufR (static), stages bufW (static) for the
    // NEXT tile.  Invariant entering a tile: 2 outstanding loads = bufR.a1,a3
    // (gated mid-tile by vmcnt(4) before P3 reads them); exiting: 2 outstanding
    // = bufW.a1,a3 (vmcnt(2) retires bufW's first 6 for the next tile's P1).
#define GTILE(AsR, BsR, AsW, BsW, kw, dopf)                                   \
  do {                                                                        \
    shortx8 aF[4][2], bF[2][2];                                               \
    _Pragma("unroll") for (int mi = 0; mi < 4; ++mi) {                        \
        aF[mi][0] = *(const shortx8*)&AsR[aoff + mi * 1024 + go0];            \
        aF[mi][1] = *(const shortx8*)&AsR[aoff + mi * 1024 + go1];            \
    }                                                                         \
    _Pragma("unroll") for (int ni = 0; ni < 2; ++ni) {                        \
        bF[ni][0] = *(const shortx8*)&BsR[boff + ni * 1024 + go0];            \
        bF[ni][1] = *(const shortx8*)&BsR[boff + ni * 1024 + go1];            \
    }                                                                         \
    if (dopf) { STG(AsW, srcA, 0, kw); STG(AsW, srcA, 2, kw); }               \
    __builtin_amdgcn_s_barrier();                                             \
    asm volatile("s_waitcnt lgkmcnt(0)" ::: "memory");                        \
    __builtin_amdgcn_s_setprio(1);                                            \
    _Pragma("unroll") for (int mi = 0; mi < 4; ++mi)                          \
        _Pragma("unroll") for (int ni = 0; ni < 2; ++ni)                      \
            acc[mi][ni] = mfma2(aF[mi][0], aF[mi][1], bF[ni][0], bF[ni][1],   \
                                acc[mi][ni]);                                 \
    __builtin_amdgcn_s_setprio(0);                                            \
    __builtin_amdgcn_s_barrier();                                             \
    _Pragma("unroll") for (int ni = 0; ni < 2; ++ni) {                        \
        bF[ni][0] = *(const shortx8*)&BsR[boff + (ni + 2) * 1024 + go0];      \
        bF[ni][1] = *(const shortx8*)&BsR[boff + (ni + 2) * 1024 + go1];      \
    }                                                                         \
    if (dopf) { STG(BsW, srcB, 0, kw); STG(BsW, srcB, 1, kw); }               \
    __builtin_amdgcn_s_barrier();                                             \
    asm volatile("s_waitcnt lgkmcnt(0)" ::: "memory");                        \
    __builtin_amdgcn_s_setprio(1);                                            \
    _Pragma("unroll") for (int mi = 0; mi < 4; ++mi)                          \
        _Pragma("unroll") for (int ni = 0; ni < 2; ++ni)                      \
            acc[mi][ni + 2] = mfma2(aF[mi][0], aF[mi][1], bF[ni][0],          \
                                    bF[ni][1], acc[mi][ni + 2]);              \
    __builtin_amdgcn_s_setprio(0);                                            \
    if (dopf) asm volatile("s_waitcnt vmcnt(4)" ::: "memory");                \
    else      asm volatile("s_waitcnt vmcnt(0)" ::: "memory");                \
    __builtin_amdgcn_s_barrier();                                             \
    _Pragma("unroll") for (int mi = 0; mi < 4; ++mi) {                        \
        aF[mi][0] = *(const shortx8*)&AsR[aoff + (mi + 4) * 1024 + go0];      \
        aF[mi][1] = *(const shortx8*)&AsR[aoff + (mi + 4) * 1024 + go1];      \
    }                                                                         \
    if (dopf) { STG(BsW, srcB, 2, kw); STG(BsW, srcB, 3, kw); }               \
    __builtin_amdgcn_s_barrier();                                             \
    asm volatile("s_waitcnt lgkmcnt(0)" ::: "memory");                        \
    __builtin_amdgcn_s_setprio(1);                                            \
    _Pragma("unroll") for (int mi = 0; mi < 4; ++mi)                          \
        _Pragma("unroll") for (int ni = 0; ni < 2; ++ni)                      \
            acc[mi + 4][ni + 2] = mfma2(aF[mi][0], aF[mi][1], bF[ni][0],      \
                                        bF[ni][1], acc[mi + 4][ni + 2]);      \
    __builtin_amdgcn_s_setprio(0);                                            \
    __builtin_amdgcn_s_barrier();                                             \
    _Pragma("unroll") for (int ni = 0; ni < 2; ++ni) {                        \
        bF[ni][0] = *(const shortx8*)&BsR[boff + ni * 1024 + go0];            \
        bF[ni][1] = *(const shortx8*)&BsR[boff + ni * 1024 + go1];            \
    }                                                                         \
    if (dopf) { STG(AsW, srcA, 1, kw); STG(AsW, srcA, 3, kw); }               \
    __builtin_amdgcn_s_barrier();                                             \
    asm volatile("s_waitcnt lgkmcnt(0)" ::: "memory");                        \
    __builtin_amdgcn_s_setprio(1);                                            \
    _Pragma("unroll") for (int mi = 0; mi < 4; ++mi)                          \
        _Pragma("unroll") for (int ni = 0; ni < 2; ++ni)                      \
            acc[mi + 4][ni] = mfma2(aF[mi][0], aF[mi][1], bF[ni][0],          \
                                    bF[ni][1], acc[mi + 4][ni]);              \
    __builtin_amdgcn_s_setprio(0);                                            \
    if (dopf) asm volatile("s_waitcnt vmcnt(2)" ::: "memory");                \
    __builtin_amdgcn_s_barrier();                                             \
  } while (0)

    const int NH = NT >> 1;
    for (int u = 0; u < NH; ++u) {
        // even tile: read buf0, stage buf1 (always a next tile: NT even)
        GTILE(As0, Bs0, As1, Bs1, ((2 * u + 1) << 6), true);
        // odd tile: read buf1, stage buf0 for the next pair (unless last)
        const bool pf2 = (u + 1) < NH;
        GTILE(As1, Bs1, As0, Bs0, ((2 * u + 2) << 6), pf2);
    }
#undef GTILE
#undef STG

    // epilogue (m89 C/D layout: col = l16, row = quad*4 + r)
#pragma unroll
    for (int mi = 0; mi < 8; ++mi) {
#pragma unroll
        for (int ni = 0; ni < 4; ++ni) {
            const size_t row0 = bm + wm * 128 + mi * 16 + quad * 4;
            const size_t col  = bn + wn * 64 + ni * 16 + l16;
#pragma unroll
            for (int r = 0; r < 4; ++r) {
                float v = acc[mi][ni][r];
                const size_t idx = (row0 + r) * (size_t)N + col;
                if (EPI == 0) {
                    Cb[idx] = f2bf(v);
                } else if (EPI == 1) {
                    v += bias[col];
                    Cb[idx] = f2bf(v > 0.f ? v : 0.f);
                } else if (EPI == 2) {
                    Cf[idx] = resid[idx] + v;
                } else if (EPI == 3) {
                    v += bias[col];
                    Cf[idx] = resid[idx] + v;
                } else {
                    if (sp == 0) v += bias[col];
                    atomicAdd(&Cf[idx], v);
                }
            }
        }
    }
}

// =====================================================================
// V transpose: qkv v-part -> vt[b][h][64 d][2048 s] bf16
// =====================================================================
__global__ __launch_bounds__(256)
void transpose_v(const short* __restrict__ qkv, short* __restrict__ vt)
{
    __shared__ __align__(16) short tile[64][65];
    const int st = blockIdx.x, h = blockIdx.y, b = blockIdx.z;
    const int t = threadIdx.x;
    for (int i = 0; i < 2; i++) {
        const int idx = i * 256 + t;
        const int s = idx >> 3, dg = idx & 7;
        shortx8 val = *(const shortx8*)&qkv[(size_t)(b * 2048 + st * 64 + s) * 3072
                                           + 2048 + h * 64 + dg * 8];
        for (int u = 0; u < 8; u++) tile[s][dg * 8 + u] = val[u];
    }
    __syncthreads();
    const int d = t >> 2, sg = (t & 3) * 16;
    shortx8 lo, hi;
    for (int i = 0; i < 8; i++) {
        lo[i] = tile[sg + i][d];
        hi[i] = tile[sg + 8 + i][d];
    }
    const size_t base = ((size_t)(b * 16 + h) * 64 + d) * 2048 + st * 64 + sg;
    *(shortx8*)&vt[base]     = lo;
    *(shortx8*)&vt[base + 8] = hi;
}

// =====================================================================
// Flash attention v6 (unchanged): 32x32x16 MFMA, 8 waves x 32 q-rows.
// =====================================================================
__global__ __launch_bounds__(512, 4)
void attention_kernel(const short* __restrict__ qkv, const short* __restrict__ vt,
                      short* __restrict__ ctx)
{
    const int qt = blockIdx.x, h = blockIdx.y, b = blockIdx.z;
    const int tid  = threadIdx.x;
    const int wave = tid >> 6;          // 0..7
    const int lane = tid & 63;
    const int l32  = lane & 31;
    const int hf   = lane >> 5;         // 0/1

    __shared__ __align__(16) short Ks[64 * 72];        // [kseq][d], stride 72
    __shared__ __align__(16) short Vs[64 * 72];        // [d][s],   stride 72
    __shared__ __align__(16) short Ps[8][32 * 72];     // per-wave P [q][s], stride 72

    const int q0 = qt * 256 + wave * 32;
    const float qscale = 0.125f * 1.44269504088896f;
    const short* qrow = qkv + (size_t)(b * 2048 + q0 + l32) * 3072 + h * 64;
    shortx8 qf[4];
    for (int dk = 0; dk < 4; dk++) {
        shortx8 raw = *(const shortx8*)&qrow[dk * 16 + hf * 8];
        for (int j = 0; j < 8; j++) raw[j] = f2bf(bf2f(raw[j]) * qscale);
        qf[dk] = raw;
    }

    floatx16 accO[2];
    for (int t = 0; t < 2; t++)
        for (int r = 0; r < 16; r++) accO[t][r] = 0.f;
    float lsum = 0.f;

    const short* kbase = qkv + (size_t)(b * 2048) * 3072 + 1024 + h * 64;
    const short* vbase = vt + ((size_t)(b * 16 + h) * 64) * 2048;
    short* const psw = &Ps[wave][0];
    unsigned* const pswd = (unsigned*)psw;

    const int ss = tid >> 3, sdg = tid & 7;

    for (int kt = 0; kt < 32; ++kt) {
        __syncthreads();
        {
            shortx8 kv = *(const shortx8*)&kbase[(size_t)(kt * 64 + ss) * 3072 + sdg * 8];
            *(shortx8*)&Ks[ss * 72 + sdg * 8] = kv;
            shortx8 vv = *(const shortx8*)&vbase[(size_t)ss * 2048 + kt * 64 + sdg * 8];
            *(shortx8*)&Vs[ss * 72 + sdg * 8] = vv;
        }
        __syncthreads();

        for (int t = 0; t < 2; t++) {
            floatx16 c;
            for (int r = 0; r < 16; r++) c[r] = 0.f;
            for (int dk = 0; dk < 4; dk++) {
                shortx8 kf = *(const shortx8*)&Ks[(t * 32 + l32) * 72 + dk * 16 + hf * 8];
                c = __builtin_amdgcn_mfma_f32_32x32x16_bf16(kf, qf[dk], c, 0, 0, 0);
            }
            for (int R = 0; R < 4; R++) {
                float2 a, bb;
                a.x  = fast_exp2(c[4 * R + 0]);
                a.y  = fast_exp2(c[4 * R + 1]);
                bb.x = fast_exp2(c[4 * R + 2]);
                bb.y = fast_exp2(c[4 * R + 3]);
                lsum += (a.x + a.y) + (bb.x + bb.y);
                union { __hip_bfloat162 h2[2]; uint2 u; } pk;
                pk.h2[0] = __float22bfloat162_rn(a);
                pk.h2[1] = __float22bfloat162_rn(bb);
                *(uint2*)&pswd[l32 * 36 + t * 16 + 4 * R + 2 * hf] = pk.u;
            }
        }
        asm volatile("s_waitcnt lgkmcnt(0)" ::: "memory");

        shortx8 pf[4];
        for (int sk = 0; sk < 4; sk++)
            pf[sk] = *(const shortx8*)&psw[l32 * 72 + sk * 16 + hf * 8];

        for (int t = 0; t < 2; t++) {
            floatx16 c = accO[t];
            for (int sk = 0; sk < 4; sk++) {
                shortx8 vf = *(const shortx8*)&Vs[(t * 32 + l32) * 72 + sk * 16 + hf * 8];
                c = __builtin_amdgcn_mfma_f32_32x32x16_bf16(vf, pf[sk], c, 0, 0, 0);
            }
            accO[t] = c;
        }
    }

    const float lfull = lsum + __shfl_xor(lsum, 32);
    const float inv = 1.0f / lfull;
    const size_t crow = (size_t)(b * 2048 + q0 + l32) * 1024 + h * 64;
    for (int t = 0; t < 2; t++)
        for (int R = 0; R < 4; R++) {
            float2 a, bb;
            a.x  = accO[t][4 * R + 0] * inv;
            a.y  = accO[t][4 * R + 1] * inv;
            bb.x = accO[t][4 * R + 2] * inv;
            bb.y = accO[t][4 * R + 3] * inv;
            union { __hip_bfloat162 h2[2]; uint2 u; } pk;
            pk.h2[0] = __float22bfloat162_rn(a);
            pk.h2[1] = __float22bfloat162_rn(bb);
            *(uint2*)&ctx[crow + t * 32 + 8 * R + 4 * hf] = pk.u;
        }
}

// =====================================================================
// launch
// =====================================================================
extern "C" void kernel_launch(void* const* d_in, const int* in_sizes, int n_in,
                              void* d_out, int out_size, void* d_ws, size_t ws_size,
                              hipStream_t stream)
{
    const float* x   = (const float*)d_in[0];
    const float* Wq  = (const float*)d_in[1];
    const float* Wk  = (const float*)d_in[2];
    const float* Wv  = (const float*)d_in[3];
    const float* Wo  = (const float*)d_in[4];
    const float* W1  = (const float*)d_in[5];
    const float* b1  = (const float*)d_in[6];
    const float* W2  = (const float*)d_in[7];
    const float* b2  = (const float*)d_in[8];
    const float* g1  = (const float*)d_in[9];
    const float* be1 = (const float*)d_in[10];
    const float* g2  = (const float*)d_in[11];
    const float* be2 = (const float*)d_in[12];
    float* out = (float*)d_out;
    char*  ws  = (char*)d_ws;

    const size_t MiB = 1u << 20;
    short* regA   = (short*)(ws);                 // 16 MiB: ln1 -> ctx -> ln2
    short* qkv    = (short*)(ws + 16 * MiB);      // 48 MiB
    short* vt     = (short*)(ws + 64 * MiB);      // 16 MiB
    short* ff1    = qkv;                          // 64 MiB alias (qkv+vt dead)
    short* Wqkv_t = (short*)(ws + 80 * MiB);      // 6 MiB
    short* Wo_t   = (short*)(ws + 86 * MiB);      // 2 MiB
    short* W1_t   = (short*)(ws + 88 * MiB);      // 8 MiB
    short* W2_t   = (short*)(ws + 96 * MiB);      // 8 MiB  (total 104 MiB)

    const dim3 blk(256);
    const unsigned LDSB = 131072;                 // 128 KiB dynamic LDS

    static int attr_once = []() {
        hipFuncSetAttribute(reinterpret_cast<const void*>(gemm256<0>),
                            hipFuncAttributeMaxDynamicSharedMemorySize, 131072);
        hipFuncSetAttribute(reinterpret_cast<const void*>(gemm256<1>),
                            hipFuncAttributeMaxDynamicSharedMemorySize, 131072);
        hipFuncSetAttribute(reinterpret_cast<const void*>(gemm256<2>),
                            hipFuncAttributeMaxDynamicSharedMemorySize, 131072);
        hipFuncSetAttribute(reinterpret_cast<const void*>(gemm256<4>),
                            hipFuncAttributeMaxDynamicSharedMemorySize, 131072);
        return 0;
    }();
    (void)attr_once;

    // weights -> bf16 BT layout
    transpose_w<<<dim3(32, 32),  blk, 0, stream>>>(Wq, Wqkv_t,                  1024, 1024);
    transpose_w<<<dim3(32, 32),  blk, 0, stream>>>(Wk, Wqkv_t + 1024 * 1024,    1024, 1024);
    transpose_w<<<dim3(32, 32),  blk, 0, stream>>>(Wv, Wqkv_t + 2 * 1024 * 1024,1024, 1024);
    transpose_w<<<dim3(32, 32),  blk, 0, stream>>>(Wo, Wo_t,                    1024, 1024);
    transpose_w<<<dim3(128, 32), blk, 0, stream>>>(W1, W1_t,                    1024, 4096);
    transpose_w<<<dim3(32, 128), blk, 0, stream>>>(W2, W2_t,                    4096, 1024);

    // LN1
    ln_bf16<<<8192, blk, 0, stream>>>(x, g1, be1, regA);
    // QKV: [8192,1024] @ [3072,1024]^T  -> 32x12 = 384 WGs
    gemm256<0><<<dim3(384), dim3(512), LDSB, stream>>>(regA, Wqkv_t, qkv, nullptr,
                                                       nullptr, nullptr, 8192, 3072, 1024, 12, 1);
    // V^T
    transpose_v<<<dim3(32, 16, 4), blk, 0, stream>>>(qkv, vt);
    // attention -> ctx (regA)
    attention_kernel<<<dim3(8, 16, 4), dim3(512), 0, stream>>>(qkv, vt, regA);
    // attn_out @ Wo + x -> out (fp32): 32x4 = 128 WGs
    gemm256<2><<<dim3(128), dim3(512), LDSB, stream>>>(regA, Wo_t, nullptr, out,
                                                       nullptr, x, 8192, 1024, 1024, 4, 1);
    // LN2 -> regA
    ln_bf16<<<8192, blk, 0, stream>>>(out, g2, be2, regA);
    // FF1: relu(ln2 @ W1 + b1) -> ff1 (bf16): 32x16 = 512 WGs
    gemm256<1><<<dim3(512), dim3(512), LDSB, stream>>>(regA, W1_t, ff1, nullptr,
                                                       b1, nullptr, 8192, 4096, 1024, 16, 1);
    // FF2: out += ff1 @ W2 + b2  -- split-K=2, atomic accumulation into out
    // (out already holds attn_residual from the Wo GEMM): 32x4x2 = 256 WGs
    gemm256<4><<<dim3(256), dim3(512), LDSB, stream>>>(ff1, W2_t, nullptr, out,
                                                       b2, nullptr, 8192, 1024, 4096, 4, 2);
}